// Round 3
// baseline (24735.963 us; speedup 1.0000x reference)
//
#include <hip/hip_runtime.h>
#include <math.h>

#define A_ 64
#define B_ 256
#define D_ 128
#define H_ 512
#define STEPS_ENC 64
#define STEPS_TOT (64 + 16384)   // 64 encoder steps + 256*64 decoder steps
#define NWG 32
#define WAVES_C 8                // compute waves per WG (2 units each)
#define NTHREADS 576             // 8 compute waves + 1 storer wave

// s_getreg immediate: id | offset<<6 | (width-1)<<11 ; HW_REG_XCC_ID = 20
#define XCC_GETREG_IMM (20 | (31 << 11))

// workspace layout (float offsets) — kept identical to prior session for safety
#define OFF_XT    0
#define N_XT      (A_*D_*B_)
#define OFF_HT0   (OFF_XT + N_XT)
#define OFF_HT1   (OFF_HT0 + H_*B_)
#define OFF_CT    (OFF_HT1 + H_*B_)
#define OFF_HTAP  (OFF_CT + H_*B_)        // decoder h taps [256][512]
#define OFF_HB64  (OFF_HTAP + B_*H_)      // tagged h [2][512] u64
#define OFF_CINIT (OFF_HB64 + 4*H_)
#define OFF_ELECT (OFF_CINIT + H_)        // ints: [0..7] per-XCD counters, [8] winner

// tanh(x) = 1 - 2/(e^{2x}+1); exact at saturation
__device__ __forceinline__ float tanhfast(float x) {
  return 1.0f - 2.0f * __builtin_amdgcn_rcpf(__expf(2.0f * x) + 1.0f);
}

// nt load: no L1 allocation => never hits a stale L1 line; served by the
// XCD-shared L2 (all decoder WGs are elected onto one XCD).
__device__ __forceinline__ unsigned long long load_nt(const unsigned long long* p) {
  unsigned long long v;
  asm volatile("global_load_dwordx2 %0, %1, off nt\n\ts_waitcnt vmcnt(0)"
               : "=&v"(v) : "v"(p) : "memory");
  return v;
}
// liveness fallback: L1 invalidate + load. Used 1/64 spins.
__device__ __forceinline__ unsigned long long load_inv(const unsigned long long* p) {
  unsigned long long v;
  asm volatile("buffer_inv sc0\n\t"
               "global_load_dwordx2 %0, %1, off nt\n\ts_waitcnt vmcnt(0)"
               : "=&v"(v) : "v"(p) : "memory");
  return v;
}
// nt store: write-through to shared L2, no L1 allocate.
__device__ __forceinline__ void store_nt(unsigned long long* p, unsigned long long v) {
  asm volatile("global_store_dwordx2 %0, %1, off nt" :: "v"(p), "v"(v) : "memory");
}

// DPP add helper: x += dpp_sel(x). All VALU-speed.
template<int CTRL>
__device__ __forceinline__ float dpp_add(float x) {
  int y = __builtin_amdgcn_update_dpp(0, __float_as_int(x), CTRL, 0xF, 0xF, false);
  return x + __int_as_float(y);
}
// 8-lane group all-sum: half_mirror (i+=7-i), quad xor2, quad xor1.
// After half_mirror each 4-lane quad holds all four pair-sums; the two
// quad_perm steps complete the total in every lane of the 8-group.
__device__ __forceinline__ float grp8_allsum(float x) {
  x = dpp_add<0x141>(x);   // row_half_mirror
  x = dpp_add<0x4E>(x);    // quad_perm [2,3,0,1]  (xor 2)
  x = dpp_add<0xB1>(x);    // quad_perm [1,0,3,2]  (xor 1)
  return x;
}

// padded hstage: chunk c (64 floats) stored at 68c + off. 68 floats = 272 B
// = 17*16 B -> float4 reads stay 16B-aligned; the 8 distinct lane addresses
// per ds_read_b128 are 8-way broadcast + distinct banks (conflict-free).
#define HSP 68
#define HS_N 544

// ---------------------------------------------------------------------------
// init0: seed tagged h (tag 0 = zero-state in parity 1, invalid in parity 0),
// reset election. Encoder h0/c0 are zeros so tag 0 carries h=0.0f.
// ---------------------------------------------------------------------------
__global__ void init0(float* __restrict__ ws) {
  unsigned long long* HB = (unsigned long long*)(ws + OFF_HB64);
  int* EL = (int*)(ws + OFF_ELECT);
  int j = threadIdx.x;                 // 512 threads
  HB[H_ + j] = 0ull;                   // parity 1: tag 0, h = 0.0f
  HB[j]      = 0xFFFFFFFF00000000ull;  // parity 0: invalid
  if (j < 8) EL[j] = 0;
  if (j == 8) EL[8] = -1;              // winner xcd
}

// ---------------------------------------------------------------------------
// Compute-wave phase. Wave v owns units 2v, 2v+1 of the WG's 16.
// Lane l: group q = l>>3 selects (unit n = l>>5, gate g = (l>>3)&3);
// j = l&7 covers h[64j..64j+64) and x[16j..16j+16).
// Per step: x prefetch -> global poll chunk [64v,64v+64) (1 lane/elem,
// proven tagged protocol) -> stage to padded LDS -> release-add parity
// counter -> acquire-poll counter (replaces __syncthreads) -> full-H dot
// -> 8-lane DPP reduce -> unified activation -> shfl gather -> c update
// -> tagged hn to LDS hout (storer wave handles all global stores; compute
// waves carry NO stores in their vmcnt queue => polls never drain an ack).
// ---------------------------------------------------------------------------
template<int PHASE>
__device__ __forceinline__ void lstm_phase(
    const float* __restrict__ in0,
    const float* __restrict__ Wih, const float* __restrict__ Whh,
    const float* __restrict__ bih, const float* __restrict__ bhh,
    unsigned long long* __restrict__ HB,
    float (*hstage)[HS_N], unsigned long long* hout, unsigned int* cnt,
    int w, int v, int l, float& c0, float& c1,
    float actA, float actB, float actC)
{
  const int j = l & 7;               // k-slice
  const int g = (l >> 3) & 3;        // gate 0=i 1=f 2=g~ 3=o
  const int n = l >> 5;              // unit select within the wave's pair
  const int u = (w << 4) + (v << 1) + n;
  const int R = (g << 9) + u;        // global gate row

  float4 wh[16];
#pragma unroll
  for (int k = 0; k < 16; ++k)
    wh[k] = *(const float4*)&Whh[R * H_ + (j << 6) + (k << 2)];
  float4 wx[4];
#pragma unroll
  for (int k = 0; k < 4; ++k)
    wx[k] = *(const float4*)&Wih[R * D_ + (j << 4) + (k << 2)];
  const float bias = (j == 0) ? (bih[R] + bhh[R]) : 0.f;  // counted once/row

  const int s0 = (PHASE == 0) ? 0 : STEPS_ENC;
  const int s1 = (PHASE == 0) ? STEPS_ENC : STEPS_TOT;

  for (int s = s0; s < s1; ++s) {
    // x loads — independent of h, issued before the poll to overlap
    const float* xp;
    if (PHASE == 0) {
      xp = in0 + (s * B_ + 255) * D_;                     // x_t = input[t,255,:]
    } else {
      const int sd = s - STEPS_ENC;
      xp = in0 + ((sd & 63) * B_ + (255 - (sd >> 6))) * D_;
    }
    float4 x0 = *(const float4*)(xp + (j << 4));
    float4 x1 = *(const float4*)(xp + (j << 4) + 4);
    float4 x2 = *(const float4*)(xp + (j << 4) + 8);
    float4 x3 = *(const float4*)(xp + (j << 4) + 12);

    // poll h_{s-1} chunk: 64 elements, one lane each (nt; inv 1/64 spins)
    unsigned long long* slot = &HB[(((s + 1) & 1) << 9) + (v << 6) + l];
    unsigned long long pk;
    int spins = 0;
    for (;;) {
      pk = ((++spins & 63) == 0) ? load_inv(slot) : load_nt(slot);
      if (__all((unsigned)(pk >> 32) == (unsigned)s)) break;
    }
    float* hbuf = hstage[s & 1];
    hbuf[v * HSP + l] = __uint_as_float((unsigned)pk);

    // bias + x contribution while the stage settles
    float acc = bias
              + wx[0].x * x0.x + wx[0].y * x0.y + wx[0].z * x0.z + wx[0].w * x0.w
              + wx[1].x * x1.x + wx[1].y * x1.y + wx[1].z * x1.z + wx[1].w * x1.w
              + wx[2].x * x2.x + wx[2].y * x2.y + wx[2].z * x2.z + wx[2].w * x2.w
              + wx[3].x * x3.x + wx[3].y * x3.y + wx[3].z * x3.z + wx[3].w * x3.w;

    // release: this wave's 64 staged floats are visible before the count
    if (l == 0)
      __hip_atomic_fetch_add(&cnt[s & 1], 1u, __ATOMIC_RELEASE,
                             __HIP_MEMORY_SCOPE_WORKGROUP);
    // acquire-poll: all 8 chunks staged for this step (replaces barrier)
    const unsigned target = 8u * ((unsigned)(s >> 1) + 1u);
    while (__hip_atomic_load(&cnt[s & 1], __ATOMIC_ACQUIRE,
                             __HIP_MEMORY_SCOPE_WORKGROUP) < target) {}

    // full-H dot: lane j reads h[64j..64j+64) (16B-aligned, broadcast)
    const float4* hp = (const float4*)&hbuf[j * HSP];
#pragma unroll
    for (int k = 0; k < 16; ++k) {
      float4 h4 = hp[k];
      acc += wh[k].x * h4.x + wh[k].y * h4.y + wh[k].z * h4.z + wh[k].w * h4.w;
    }

    // 8-lane all-sum within each (unit,gate) group
    float a = grp8_allsum(acc);
    // unified activation: i,f,o -> sigmoid; g~ -> tanh (per-lane constants)
    a = fmaf(actA, __builtin_amdgcn_rcpf(__expf(actB * a) + 1.0f), actC);
    // gather the 8 group sums (gate g of unit n sits at lane 32n + 8g)
    float ai0 = __shfl(a, 0),  af0 = __shfl(a, 8);
    float ag0 = __shfl(a, 16), ao0 = __shfl(a, 24);
    float ai1 = __shfl(a, 32), af1 = __shfl(a, 40);
    float ag1 = __shfl(a, 48), ao1 = __shfl(a, 56);
    c0 = af0 * c0 + ai0 * ag0;
    c1 = af1 * c1 + ai1 * ag1;
    float hn0 = ao0 * tanhfast(c0);
    float hn1 = ao1 * tanhfast(c1);
    if (l == 0) {
      const unsigned long long t = ((unsigned long long)(unsigned)(s + 1) << 32);
      __hip_atomic_store(&hout[(v << 1)],     t | __float_as_uint(hn0),
                         __ATOMIC_RELAXED, __HIP_MEMORY_SCOPE_WORKGROUP);
      __hip_atomic_store(&hout[(v << 1) + 1], t | __float_as_uint(hn1),
                         __ATOMIC_RELAXED, __HIP_MEMORY_SCOPE_WORKGROUP);
    }
  }
}

// ---------------------------------------------------------------------------
// fused persistent kernel: 256 WGs launched; the 32 on one elected XCD run
// 64 encoder + 16384 decoder sequential steps; others exit.
// Wave 8 = storer: LDS-polls the 16 tagged hout slots, then issues ONE
// coalesced 128B tagged store (and the HTAP tap). Its store acks drain off
// the critical path; it never loads from global, so never waits on vmcnt.
// ---------------------------------------------------------------------------
__global__ __launch_bounds__(NTHREADS) void fused(
    const float* __restrict__ in0,
    const float* __restrict__ eWih, const float* __restrict__ eWhh,
    const float* __restrict__ ebih, const float* __restrict__ ebhh,
    const float* __restrict__ dWih, const float* __restrict__ dWhh,
    const float* __restrict__ dbih, const float* __restrict__ dbhh,
    float* __restrict__ ws)
{
  unsigned long long* HB = (unsigned long long*)(ws + OFF_HB64);
  float* HTAP = ws + OFF_HTAP;

  __shared__ __align__(16) float hstage[2][HS_N];   // parity double-buffered
  __shared__ unsigned long long hout[16];           // tagged per-unit h
  __shared__ unsigned int cnt[2];                   // parity stage counters
  __shared__ int role;

  const int tid = threadIdx.x;

  // LDS init BEFORE the election barrier (the only __syncthreads; no wave
  // that might have exited ever needs to rendezvous again).
  if (tid < 16) hout[tid] = 0xFFFFFFFF00000000ull;
  if (tid < 2)  cnt[tid] = 0u;

  // ---- election: first XCD to seat 32 WGs wins; its ranks 0..31 decode ----
  if (tid == 0) {
    unsigned xcc = ((unsigned)__builtin_amdgcn_s_getreg(XCC_GETREG_IMM)) & 7u;
    int* EL = (int*)(ws + OFF_ELECT);
    int r = __hip_atomic_fetch_add(&EL[xcc], 1, __ATOMIC_RELAXED,
                                   __HIP_MEMORY_SCOPE_AGENT);
    int myrole = -1;
    if (r < NWG) {
      if (r == NWG - 1) {
        int exp = -1;
        __hip_atomic_compare_exchange_strong(&EL[8], &exp, (int)xcc,
            __ATOMIC_RELAXED, __ATOMIC_RELAXED, __HIP_MEMORY_SCOPE_AGENT);
      }
      int wx;
      do {
        wx = __hip_atomic_load(&EL[8], __ATOMIC_RELAXED, __HIP_MEMORY_SCOPE_AGENT);
        if (wx == -1) __builtin_amdgcn_s_sleep(2);
      } while (wx == -1);
      if (wx == (int)xcc) myrole = r;
    }
    role = myrole;
  }
  __syncthreads();
  if (role < 0) return;               // uniform per WG
  const int w = role;

  const int wid = tid >> 6;
  const int l = tid & 63;

  if (wid == WAVES_C) {
    // ---------------- storer wave ----------------
    const int u = (w << 4) + (l & 15);
    for (int s = 0; s < STEPS_TOT; ++s) {
      unsigned long long pk;
      for (;;) {
        pk = (l < 16)
           ? __hip_atomic_load(&hout[l & 15], __ATOMIC_ACQUIRE,
                               __HIP_MEMORY_SCOPE_WORKGROUP)
           : (((unsigned long long)(unsigned)(s + 1)) << 32);
        if (__all((unsigned)(pk >> 32) == (unsigned)(s + 1))) break;
      }
      if (l < 16) {
        if ((s & 63) == 63) {
          int q = s >> 6;
          if (q < 256) HTAP[q * H_ + u] = __uint_as_float((unsigned)pk);
        }
        store_nt(&HB[((s & 1) << 9) + u], pk);  // 16 lanes: one 128B store
      }
    }
    return;
  }

  // ---------------- compute waves ----------------
  const int v = wid;                  // 0..7, owns units 2v,2v+1

  // per-lane unified-activation constants by gate ((l>>3)&3): 2 = g~ (tanh)
  const int gate = (l >> 3) & 3;
  const float actA = (gate == 2) ? -2.0f :  1.0f;
  const float actB = (gate == 2) ?  2.0f : -1.0f;
  const float actC = (gate == 2) ?  1.0f :  0.0f;

  float c0 = 0.f, c1 = 0.f;           // encoder starts from h0 = c0 = 0

  lstm_phase<0>(in0, eWih, eWhh, ebih, ebhh, HB, hstage, hout, cnt,
                w, v, l, c0, c1, actA, actB, actC);
  lstm_phase<1>(in0, dWih, dWhh, dbih, dbhh, HB, hstage, hout, cnt,
                w, v, l, c0, c1, actA, actB, actC);
}

// ---------------------------------------------------------------------------
// out_proj: outs[255-b] = Htap[255-b] @ lin_W^T + lin_b, broadcast over a.
// ---------------------------------------------------------------------------
__global__ __launch_bounds__(128) void out_proj(
    const float* __restrict__ ws, const float* __restrict__ linW,
    const float* __restrict__ linb, float* __restrict__ out) {
  const float* HTAP = ws + OFF_HTAP;
  __shared__ float hs[H_];
  const int b = blockIdx.x;
  const int i = 255 - b;
  const int d = threadIdx.x;
  *(float4*)&hs[4 * d] = *(const float4*)&HTAP[i * H_ + 4 * d];
  __syncthreads();
  float acc = linb[d];
#pragma unroll 8
  for (int k = 0; k < H_; k += 4) {
    float4 w4 = *(const float4*)&linW[d * H_ + k];
    acc += w4.x * hs[k] + w4.y * hs[k + 1] + w4.z * hs[k + 2] + w4.w * hs[k + 3];
  }
  for (int a = 0; a < A_; ++a)
    out[(a * B_ + b) * D_ + d] = acc;
}

// ---------------------------------------------------------------------------
extern "C" void kernel_launch(void* const* d_in, const int* in_sizes, int n_in,
                              void* d_out, int out_size, void* d_ws, size_t ws_size,
                              hipStream_t stream) {
  const float* in0  = (const float*)d_in[0];
  const float* eWih = (const float*)d_in[1];
  const float* eWhh = (const float*)d_in[2];
  const float* ebih = (const float*)d_in[3];
  const float* ebhh = (const float*)d_in[4];
  const float* dWih = (const float*)d_in[5];
  const float* dWhh = (const float*)d_in[6];
  const float* dbih = (const float*)d_in[7];
  const float* dbhh = (const float*)d_in[8];
  const float* linW = (const float*)d_in[9];
  const float* linb = (const float*)d_in[10];
  float* ws = (float*)d_ws;
  float* out = (float*)d_out;

  init0<<<1, 512, 0, stream>>>(ws);
  fused<<<256, NTHREADS, 0, stream>>>(in0, eWih, eWhh, ebih, ebhh,
                                      dWih, dWhh, dbih, dbhh, ws);
  out_proj<<<256, 128, 0, stream>>>(ws, linW, linb, out);
}

// Round 4
// 18984.344 us; speedup vs baseline: 1.3030x; 1.3030x over previous
//
#include <hip/hip_runtime.h>
#include <math.h>

#define A_ 64
#define B_ 256
#define D_ 128
#define H_ 512
#define STEPS_ENC 64
#define STEPS_TOT (64 + 16384)   // 64 encoder steps + 256*64 decoder steps
#define NWG 32
#define NTHREADS 1024            // 16 waves, 1 hidden unit each

// s_getreg immediate: id | offset<<6 | (width-1)<<11 ; HW_REG_XCC_ID = 20
#define XCC_GETREG_IMM (20 | (31 << 11))

// workspace layout (float offsets) — kept identical to prior session for safety
#define OFF_XT    0
#define N_XT      (A_*D_*B_)
#define OFF_HT0   (OFF_XT + N_XT)
#define OFF_HT1   (OFF_HT0 + H_*B_)
#define OFF_CT    (OFF_HT1 + H_*B_)
#define OFF_HTAP  (OFF_CT + H_*B_)        // decoder h taps [256][512]
#define OFF_HB64  (OFF_HTAP + B_*H_)      // tagged h [2][512] u64
#define OFF_CINIT (OFF_HB64 + 4*H_)
#define OFF_ELECT (OFF_CINIT + H_)        // ints: [0..7] per-XCD counters, [8] winner

// tanh(x) = 1 - 2/(e^{2x}+1); exact at saturation
__device__ __forceinline__ float tanhfast(float x) {
  return 1.0f - 2.0f * __builtin_amdgcn_rcpf(__expf(2.0f * x) + 1.0f);
}

// nt load: no L1 allocation => never hits a stale L1 line; served by the
// XCD-shared L2 (all decoder WGs are elected onto one XCD).
__device__ __forceinline__ unsigned long long load_nt(const unsigned long long* p) {
  unsigned long long v;
  asm volatile("global_load_dwordx2 %0, %1, off nt\n\ts_waitcnt vmcnt(0)"
               : "=&v"(v) : "v"(p) : "memory");
  return v;
}
// liveness fallback: L1 invalidate + load. Used 1/64 spins.
__device__ __forceinline__ unsigned long long load_inv(const unsigned long long* p) {
  unsigned long long v;
  asm volatile("buffer_inv sc0\n\t"
               "global_load_dwordx2 %0, %1, off nt\n\ts_waitcnt vmcnt(0)"
               : "=&v"(v) : "v"(p) : "memory");
  return v;
}
// nt store: write-through to shared L2, no L1 allocate.
__device__ __forceinline__ void store_nt(unsigned long long* p, unsigned long long v) {
  asm volatile("global_store_dwordx2 %0, %1, off nt" :: "v"(p), "v"(v) : "memory");
}

// DPP rotate-reduce within each 16-lane row: after ror{8,4,2,1} add chain,
// EVERY lane of the row holds the 16-lane sum. VALU-speed (no LDS).
template<int CTRL>
__device__ __forceinline__ float dpp_ror_add(float x) {
  int y = __builtin_amdgcn_update_dpp(0, __float_as_int(x), CTRL, 0xF, 0xF, false);
  return x + __int_as_float(y);
}
__device__ __forceinline__ float row_allsum16(float x) {
  x = dpp_ror_add<0x128>(x);   // row_ror:8
  x = dpp_ror_add<0x124>(x);   // row_ror:4
  x = dpp_ror_add<0x122>(x);   // row_ror:2
  x = dpp_ror_add<0x121>(x);   // row_ror:1
  return x;
}

// padded hstage: chunk v (32 floats) stored at 36v + off (R2-proven: stage
// writes hit all 32 banks; dot reads are 2-way/broadcast = conflict-free).
#define HSP 36
#define HS_N (16 * HSP)

// unified x address for both phases (encoder t on batch row 255, then the
// decoder's column-reversed scan). Keeps the prefetch continuous across the
// phase boundary.
__device__ __forceinline__ const float* xaddr(const float* in0, int s) {
  if (s < STEPS_ENC) return in0 + (s * B_ + 255) * D_;
  int sd = s - STEPS_ENC;
  return in0 + ((sd & 63) * B_ + (255 - (sd >> 6))) * D_;
}

// ---------------------------------------------------------------------------
// init0: seed tagged h (tag 0 = zero-state in parity 1, invalid in parity 0),
// reset election. Encoder h0/c0 are zeros so tag 0 carries h=0.0f.
// ---------------------------------------------------------------------------
__global__ void init0(float* __restrict__ ws) {
  unsigned long long* HB = (unsigned long long*)(ws + OFF_HB64);
  int* EL = (int*)(ws + OFF_ELECT);
  int j = threadIdx.x;                 // 512 threads
  HB[H_ + j] = 0ull;                   // parity 1: tag 0, h = 0.0f
  HB[j]      = 0xFFFFFFFF00000000ull;  // parity 0: invalid
  if (j < 8) EL[j] = 0;
  if (j == 8) EL[8] = -1;              // winner xcd
}

// ---------------------------------------------------------------------------
// One LSTM recurrence phase, R2 skeleton (wave v owns unit u = 16w+v; lane
// (g = l>>4, j = l&15) holds gate-row R = g*512+u over h[32j,32j+32) and
// x[8j,8j+8)). R4 changes, each attacking the measured ~2900cy/step chain:
//   1. x is REGISTER-PREFETCHED one step ahead (issued right after this
//      step's stage+release) so the poll's vmcnt(0) never eats x latency
//      (plain x loads were L2/L3-served every step due to buffer_inv L1
//      thrash — a constant ~300-500cy term at the poll head in R0-R2).
//   2. __syncthreads -> LDS release/acquire parity counter: no per-step
//      vmcnt/lgkm drain, so the prefetch stays in flight across the
//      handshake. Safety: a wave can release s+2 only after all waves
//      released s+1 (acquire chain), which implies every dot of step s
//      finished -> hstage[s&1] and HB parity slots are overwrite-safe.
//   3. producer wave stores its own unit immediately (R3's storer hand-off
//      cost ~700cy; scattered-store write amplification is BW-irrelevant).
// ---------------------------------------------------------------------------
template<int PHASE>
__device__ __forceinline__ void lstm_phase(
    const float* __restrict__ in0,
    const float* __restrict__ Wih, const float* __restrict__ Whh,
    const float* __restrict__ bih, const float* __restrict__ bhh,
    unsigned long long* __restrict__ HB, float* __restrict__ HTAP,
    float (*hstage)[HS_N], unsigned int* cnt,
    int w, int v, int l, float& c, float4 (&xc)[2],
    float actA, float actB, float actC)
{
  const int g = l >> 4;              // gate: 0=i 1=f 2=g~ 3=o
  const int j = l & 15;              // reduction lane / k-slice
  const int u = (w << 4) + v;        // hidden unit owned by this wave
  const int R = (g << 9) + u;        // global gate row

  float4 wh[8];
#pragma unroll
  for (int k = 0; k < 8; ++k)
    wh[k] = *(const float4*)&Whh[R * H_ + (j << 5) + (k << 2)];
  float4 wx0 = *(const float4*)&Wih[R * D_ + (j << 3)];
  float4 wx1 = *(const float4*)&Wih[R * D_ + (j << 3) + 4];
  const float bias = (j == 0) ? (bih[R] + bhh[R]) : 0.f;  // counted once/row

  const int pe = (v << 5) + (l & 31);   // polled element (2 lanes per element)

  const int s0 = (PHASE == 0) ? 0 : STEPS_ENC;
  const int s1 = (PHASE == 0) ? STEPS_ENC : STEPS_TOT;

  for (int s = s0; s < s1; ++s) {
    // ---- poll h_{s-1}: nt loads from shared L2; inv fallback 1/64 spins.
    // The wave's vmem queue holds only last step's store ack + long-landed
    // prefetch, so vmcnt(0) is ~clean.
    unsigned long long* slot = &HB[(((s + 1) & 1) << 9) + pe];
    unsigned long long pk;
    int spins = 0;
    for (;;) {
      pk = ((++spins & 63) == 0) ? load_inv(slot) : load_nt(slot);
      if (__all((unsigned)(pk >> 32) == (unsigned)s)) break;
    }
    float* hbuf = hstage[s & 1];
    if (l < 32) hbuf[v * HSP + (l & 31)] = __uint_as_float((unsigned)pk);

    // ---- release: stage visible before the count (REL orders LDS writes)
    if (l == 0)
      __hip_atomic_fetch_add(&cnt[s & 1], 1u, __ATOMIC_RELEASE,
                             __HIP_MEMORY_SCOPE_WORKGROUP);

    // ---- bias + x-partial from registers prefetched LAST step
    float acc0 = bias
               + wx0.x * xc[0].x + wx0.y * xc[0].y
               + wx0.z * xc[0].z + wx0.w * xc[0].w
               + wx1.x * xc[1].x + wx1.y * xc[1].y
               + wx1.z * xc[1].z + wx1.w * xc[1].w;

    // ---- prefetch x(s+1): lands during acquire+dot, read next step
    int sn = s + 1; if (sn >= STEPS_TOT) sn = STEPS_TOT - 1;  // clamp tail
    const float* xp = xaddr(in0, sn);
    float4 xn0 = *(const float4*)(xp + (j << 3));
    float4 xn1 = *(const float4*)(xp + (j << 3) + 4);

    // ---- acquire: all 16 chunks staged for this step (no counter drain)
    const unsigned target = 16u * ((unsigned)(s >> 1) + 1u);
    while (__hip_atomic_load(&cnt[s & 1], __ATOMIC_ACQUIRE,
                             __HIP_MEMORY_SCOPE_WORKGROUP) < target) {}

    // ---- full-H dot, dual accumulators to halve the FMA dep chain
    const float4* hp = (const float4*)&hbuf[j * HSP];
    float acc1 = 0.f;
#pragma unroll
    for (int k = 0; k < 8; k += 2) {
      float4 h4a = hp[k];
      float4 h4b = hp[k + 1];
      acc0 += wh[k].x * h4a.x + wh[k].y * h4a.y
            + wh[k].z * h4a.z + wh[k].w * h4a.w;
      acc1 += wh[k + 1].x * h4b.x + wh[k + 1].y * h4b.y
            + wh[k + 1].z * h4b.z + wh[k + 1].w * h4b.w;
    }

    // ---- 16-lane rotate-reduce; unified activation; gate gather
    float a = row_allsum16(acc0 + acc1);
    a = fmaf(actA, __builtin_amdgcn_rcpf(__expf(actB * a) + 1.0f), actC);
    float ai = __shfl(a, 0);
    float af = __shfl(a, 16);
    float ag = __shfl(a, 32);
    float ao = __shfl(a, 48);
    c = af * c + ai * ag;                 // uniform across the wave
    float hn = ao * tanhfast(c);
    if (l == 0) {
      // h taps every 64 steps: s=63 -> q=0 (encoder final), s=127 -> q=1, ...
      if ((s & 63) == 63) {
        int q = s >> 6;
        if (q < 256) HTAP[q * H_ + u] = hn;
      }
      unsigned long long opk =
          ((unsigned long long)(unsigned)(s + 1) << 32) | __float_as_uint(hn);
      store_nt(&HB[((s & 1) << 9) + u], opk);
    }
    xc[0] = xn0; xc[1] = xn1;             // rotate prefetch regs
  }
}

// ---------------------------------------------------------------------------
// fused persistent kernel: 256 WGs launched; the 32 on one elected XCD run
// 64 encoder + 16384 decoder sequential steps; others exit.
// ---------------------------------------------------------------------------
__global__ __launch_bounds__(NTHREADS) void fused(
    const float* __restrict__ in0,
    const float* __restrict__ eWih, const float* __restrict__ eWhh,
    const float* __restrict__ ebih, const float* __restrict__ ebhh,
    const float* __restrict__ dWih, const float* __restrict__ dWhh,
    const float* __restrict__ dbih, const float* __restrict__ dbhh,
    float* __restrict__ ws)
{
  unsigned long long* HB = (unsigned long long*)(ws + OFF_HB64);
  float* HTAP = ws + OFF_HTAP;

  __shared__ __align__(16) float hstage[2][HS_N];   // parity double-buffered
  __shared__ unsigned int cnt[2];                   // parity stage counters
  __shared__ int role;

  const int tid = threadIdx.x;

  if (tid < 2) cnt[tid] = 0u;   // before the (only) election barrier

  // ---- election: first XCD to seat 32 WGs wins; its ranks 0..31 decode ----
  if (tid == 0) {
    unsigned xcc = ((unsigned)__builtin_amdgcn_s_getreg(XCC_GETREG_IMM)) & 7u;
    int* EL = (int*)(ws + OFF_ELECT);
    int r = __hip_atomic_fetch_add(&EL[xcc], 1, __ATOMIC_RELAXED,
                                   __HIP_MEMORY_SCOPE_AGENT);
    int myrole = -1;
    if (r < NWG) {
      if (r == NWG - 1) {
        int exp = -1;
        __hip_atomic_compare_exchange_strong(&EL[8], &exp, (int)xcc,
            __ATOMIC_RELAXED, __ATOMIC_RELAXED, __HIP_MEMORY_SCOPE_AGENT);
      }
      int wx;
      do {
        wx = __hip_atomic_load(&EL[8], __ATOMIC_RELAXED, __HIP_MEMORY_SCOPE_AGENT);
        if (wx == -1) __builtin_amdgcn_s_sleep(2);
      } while (wx == -1);
      if (wx == (int)xcc) myrole = r;
    }
    role = myrole;
  }
  __syncthreads();
  if (role < 0) return;               // uniform per WG
  const int w = role;

  const int v = tid >> 6;             // wave -> hidden unit 16w+v
  const int l = tid & 63;             // lane

  // per-lane unified-activation constants by gate (l>>4): 0=i,1=f,2=g,3=o
  const int gate = l >> 4;
  const float actA = (gate == 2) ? -2.0f :  1.0f;
  const float actB = (gate == 2) ?  2.0f : -1.0f;
  const float actC = (gate == 2) ?  1.0f :  0.0f;

  float c = 0.f;                      // encoder starts from h0 = c0 = 0

  // prime the x pipeline for s=0
  float4 xc[2];
  {
    const int j = l & 15;
    const float* xp = xaddr(in0, 0);
    xc[0] = *(const float4*)(xp + (j << 3));
    xc[1] = *(const float4*)(xp + (j << 3) + 4);
  }

  lstm_phase<0>(in0, eWih, eWhh, ebih, ebhh, HB, HTAP, hstage, cnt,
                w, v, l, c, xc, actA, actB, actC);
  lstm_phase<1>(in0, dWih, dWhh, dbih, dbhh, HB, HTAP, hstage, cnt,
                w, v, l, c, xc, actA, actB, actC);
}

// ---------------------------------------------------------------------------
// out_proj: outs[255-b] = Htap[255-b] @ lin_W^T + lin_b, broadcast over a.
// ---------------------------------------------------------------------------
__global__ __launch_bounds__(128) void out_proj(
    const float* __restrict__ ws, const float* __restrict__ linW,
    const float* __restrict__ linb, float* __restrict__ out) {
  const float* HTAP = ws + OFF_HTAP;
  __shared__ float hs[H_];
  const int b = blockIdx.x;
  const int i = 255 - b;
  const int d = threadIdx.x;
  *(float4*)&hs[4 * d] = *(const float4*)&HTAP[i * H_ + 4 * d];
  __syncthreads();
  float acc = linb[d];
#pragma unroll 8
  for (int k = 0; k < H_; k += 4) {
    float4 w4 = *(const float4*)&linW[d * H_ + k];
    acc += w4.x * hs[k] + w4.y * hs[k + 1] + w4.z * hs[k + 2] + w4.w * hs[k + 3];
  }
  for (int a = 0; a < A_; ++a)
    out[(a * B_ + b) * D_ + d] = acc;
}

// ---------------------------------------------------------------------------
extern "C" void kernel_launch(void* const* d_in, const int* in_sizes, int n_in,
                              void* d_out, int out_size, void* d_ws, size_t ws_size,
                              hipStream_t stream) {
  const float* in0  = (const float*)d_in[0];
  const float* eWih = (const float*)d_in[1];
  const float* eWhh = (const float*)d_in[2];
  const float* ebih = (const float*)d_in[3];
  const float* ebhh = (const float*)d_in[4];
  const float* dWih = (const float*)d_in[5];
  const float* dWhh = (const float*)d_in[6];
  const float* dbih = (const float*)d_in[7];
  const float* dbhh = (const float*)d_in[8];
  const float* linW = (const float*)d_in[9];
  const float* linb = (const float*)d_in[10];
  float* ws = (float*)d_ws;
  float* out = (float*)d_out;

  init0<<<1, 512, 0, stream>>>(ws);
  fused<<<256, NTHREADS, 0, stream>>>(in0, eWih, eWhh, ebih, ebhh,
                                      dWih, dWhh, dbih, dbhh, ws);
  out_proj<<<256, 128, 0, stream>>>(ws, linW, linb, out);
}